// Round 20
// baseline (80.470 us; speedup 1.0000x reference)
//
#include <hip/hip_runtime.h>
#include <hip/hip_bf16.h>
#include <stdint.h>

typedef float f32x4 __attribute__((ext_vector_type(4)));
typedef float f32x4v __attribute__((ext_vector_type(4)));
typedef short short8 __attribute__((ext_vector_type(8)));
typedef unsigned short u16;
typedef unsigned short u16x8 __attribute__((ext_vector_type(8)));
typedef unsigned short u16x4 __attribute__((ext_vector_type(4)));

#define MFMA16x16x32 __builtin_amdgcn_mfma_f32_16x16x32_bf16

__device__ __forceinline__ u16 f2bf(float f) {
    unsigned int u = __builtin_bit_cast(unsigned int, f);
    u += 0x7fffu + ((u >> 16) & 1u);
    return (u16)(u >> 16);
}
__device__ __forceinline__ float bf2f(u16 v) {
    unsigned int u = ((unsigned int)v) << 16;
    return __builtin_bit_cast(float, u);
}

__device__ __forceinline__ void gload_lds16(const void* g, void* l) {
    __builtin_amdgcn_global_load_lds(
        (const __attribute__((address_space(1))) uint32_t*)g,
        (__attribute__((address_space(3))) uint32_t*)l, 16, 0, 0);
}

// z-blocks for the small qt of pair p (na = (p+2)>>1 kv128-tiles of the 17)
__device__ __forceinline__ int z_small128(int p) {
    int na = (p + 2) >> 1;
    int za = (8 * na + 16) / 17;
    za = za < 1 ? 1 : za;
    return za > 7 ? 7 : za;
}

// ---------------------------------------------------------------------------
// Kernel 0: W [1024,128] f32 -> WTf, MFMA-FRAGMENT-ORDERED bf16.
// Fragment f = (kt*2+ks)*24 + nc; chunk (f,lane) = 16B at WTf + f*1024 + lane*16.
// ---------------------------------------------------------------------------
__global__ void k_transpose_wf(const float* __restrict__ Wq, const float* __restrict__ Wk,
                               const float* __restrict__ Wv, u16* __restrict__ WTf) {
    int tid  = blockIdx.x * 256 + threadIdx.x;   // 0..49151
    int f    = tid >> 6;                         // 0..767
    int lane = tid & 63;
    int kt  = f / 48;
    int rem = f % 48;
    int ks  = rem / 24;
    int nc  = rem % 24;
    int col = nc * 16 + (lane & 15);
    int w   = col >> 7, n = col & 127;
    int k0  = kt * 64 + ks * 32 + (lane >> 4) * 8;
    const float* W = (w == 0) ? Wq : ((w == 1) ? Wk : Wv);
    u16x8 v;
#pragma unroll
    for (int j = 0; j < 8; ++j)
        v[j] = f2bf(W[(size_t)(k0 + j) * 128 + n]);
    *(u16x8*)(&WTf[(size_t)tid * 8]) = v;
}

// ---------------------------------------------------------------------------
// Kernel 1 (v12): FUSED QKV GEMM — gemm8's proven schedule, BIGGER M-TILE.
// BM=128, BN=192 (nh = bx&1), BK=64, grid 256, 512 thr / 8 waves (4wr x 2wc),
// wave = 32x96 (acc[2][6], identical COMPUTE shape to gemm8).
// Staged bytes drop 228->162 MB total (B re-staged per 128 rows not 64):
// per-phase DMA 40KB vs 56KB — attacks the measured gload_lds chunk-
// throughput bound.  LDS: abuf[2] 16KB + bbuf[2] 24KB = 80KB.
// Phase: ISSUEB(kt+1, 3/thr) | COMPUTE(kt) | STOREA A(kt+1) | LOADA A(kt+3)
//        (4 loads) | s_waitcnt vmcnt(4) lgkmcnt(0); s_barrier.
// vmcnt(4) keeps exactly the 4 newest A-loads, drains this phase's 3 B-DMAs.
// ---------------------------------------------------------------------------
__global__ __launch_bounds__(512) void k_qkv_gemm12(
    const float* __restrict__ x, const u16* __restrict__ WTf,
    u16* __restrict__ qb, u16* __restrict__ kb, u16* __restrict__ vT)
{
    __shared__ u16 abuf[2][128 * 64];    // 2 x 16 KB
    __shared__ u16 bbuf[2][2 * 12 * 512];// 2 x 24 KB
    const int tid  = threadIdx.x;
    const int lane = tid & 63, wid = tid >> 6;
    const int wr = wid >> 1, wc = wid & 1;
    const int lrow = lane & 15, lk = lane >> 4;
    const int nh = blockIdx.x & 1;
    const int m0 = (blockIdx.x >> 1) * 128;

    const int arow = tid >> 2;            // 0..127
    const int aseg = tid & 3;             // 0..3 (16 f32 each)
    const float* xsrc = x + (size_t)(m0 + arow) * 1024 + aseg * 16;

    f32x4 acc[2][6];
#pragma unroll
    for (int i = 0; i < 2; ++i)
#pragma unroll
        for (int j = 0; j < 6; ++j) acc[i][j] = (f32x4){0.f, 0.f, 0.f, 0.f};

#define LOADA(p0, p1, p2, p3, ktv)                                             \
    p0 = *(const f32x4v*)(xsrc + (ktv) * 64);                                  \
    p1 = *(const f32x4v*)(xsrc + (ktv) * 64 + 4);                              \
    p2 = *(const f32x4v*)(xsrc + (ktv) * 64 + 8);                              \
    p3 = *(const f32x4v*)(xsrc + (ktv) * 64 + 12);

#define STOREA(buf, p0, p1, p2, p3)                                            \
    {   u16x8 v0, v1;                                                          \
        v0[0]=f2bf(p0[0]); v0[1]=f2bf(p0[1]); v0[2]=f2bf(p0[2]); v0[3]=f2bf(p0[3]); \
        v0[4]=f2bf(p1[0]); v0[5]=f2bf(p1[1]); v0[6]=f2bf(p1[2]); v0[7]=f2bf(p1[3]); \
        v1[0]=f2bf(p2[0]); v1[1]=f2bf(p2[1]); v1[2]=f2bf(p2[2]); v1[3]=f2bf(p2[3]); \
        v1[4]=f2bf(p3[0]); v1[5]=f2bf(p3[1]); v1[6]=f2bf(p3[2]); v1[7]=f2bf(p3[3]); \
        *(u16x8*)(&buf[arow * 64 + (((2*aseg)   ^ (arow & 7)) << 3)]) = v0;     \
        *(u16x8*)(&buf[arow * 64 + (((2*aseg+1) ^ (arow & 7)) << 3)]) = v1; }

// per phase: ks 0..1 x 12 nc-local x 64 lanes x 16B = 24 KB; 3 chunks/thread
#define ISSUEB(buf, ktv)                                                       \
    {   _Pragma("unroll") for (int i = 0; i < 3; ++i) {                        \
            int c   = tid + i * 512;          /* 0..1535 */                    \
            int ks_ = c / 768;                                                 \
            int r_  = c - ks_ * 768;          /* 0..767 */                     \
            const u16* src = WTf + ((size_t)((ktv) * 2 + ks_) * 24 + nh * 12   \
                                    + (r_ >> 6)) * 512 + (r_ & 63) * 8;        \
            gload_lds16(src, &buf[c * 8]);                                     \
        } }

#define COMPUTE(ab, bb)                                                        \
    _Pragma("unroll") for (int ks = 0; ks < 2; ++ks) {                         \
        short8 af[2];                                                          \
        _Pragma("unroll") for (int mf = 0; mf < 2; ++mf) {                     \
            int row = wr * 32 + mf * 16 + lrow;                                \
            int blk = (ks * 4 + lk) ^ (row & 7);                               \
            af[mf] = *(const short8*)(&ab[row * 64 + (blk << 3)]);             \
        }                                                                      \
        _Pragma("unroll") for (int nf = 0; nf < 6; ++nf) {                     \
            short8 bfr = *(const short8*)(&bb[(ks * 12 + wc * 6 + nf) * 512 + lane * 8]); \
            _Pragma("unroll") for (int mf = 0; mf < 2; ++mf)                   \
                acc[mf][nf] = MFMA16x16x32(af[mf], bfr, acc[mf][nf], 0, 0, 0); \
        } }

#define WAITBAR()                                                              \
    asm volatile("s_waitcnt vmcnt(4) lgkmcnt(0)\n\ts_barrier" ::: "memory");   \
    __builtin_amdgcn_sched_barrier(0);

    f32x4v a0A, a1A, a2A, a3A, a0B, a1B, a2B, a3B;
    // prologue: A(0)->abuf0, issue B(0)->bbuf0, A(2)->slotA in flight
    LOADA(a0A, a1A, a2A, a3A, 0);
    LOADA(a0B, a1B, a2B, a3B, 1);
    STOREA(abuf[0], a0A, a1A, a2A, a3A); // compiler waits for A(0) regs
    ISSUEB(bbuf[0], 0);
    LOADA(a0A, a1A, a2A, a3A, 2);
    WAITBAR();                            // drains B(0); keeps A(2)

    for (int kt = 0; kt < 16; kt += 2) {
        // phase even: compute(kt) on [0]; stage A(kt+1), B(kt+1) into [1]
        {
            const int ktn = (kt + 1 < 16) ? kt + 1 : 15;
            ISSUEB(bbuf[1], ktn);
            __builtin_amdgcn_sched_barrier(0);
            COMPUTE(abuf[0], bbuf[0]);
            STOREA(abuf[1], a0B, a1B, a2B, a3B);   // A(kt+1)
            const int kp = (kt + 3 < 16) ? kt + 3 : 15;
            LOADA(a0B, a1B, a2B, a3B, kp);         // A(kt+3) -> slotB
            WAITBAR();                    // drains B(kt+1); keeps A(kt+3)
        }
        // phase odd: compute(kt+1) on [1]; stage A(kt+2), B(kt+2) into [0]
        {
            const int ktn = (kt + 2 < 16) ? kt + 2 : 15;
            ISSUEB(bbuf[0], ktn);
            __builtin_amdgcn_sched_barrier(0);
            COMPUTE(abuf[1], bbuf[1]);
            STOREA(abuf[0], a0A, a1A, a2A, a3A);   // A(kt+2)
            const int kp = (kt + 4 < 16) ? kt + 4 : 15;
            LOADA(a0A, a1A, a2A, a3A, kp);         // A(kt+4) -> slotA
            WAITBAR();                    // drains B(kt+2); keeps A(kt+4)
        }
    }
#undef LOADA
#undef STOREA
#undef ISSUEB
#undef COMPUTE
#undef WAITBAR

    // epilogue: gc in [0,384): 0..127 q, 128..255 k, 256..383 v (v transposed)
#pragma unroll
    for (int nf = 0; nf < 6; ++nf) {
        const int gc   = nh * 192 + wc * 96 + nf * 16 + lrow;
        const int wsel = gc >> 7;        // uniform per (nh,wc,nf)
        const int col  = gc & 127;
#pragma unroll
        for (int mf = 0; mf < 2; ++mf) {
            const int row0 = m0 + wr * 32 + mf * 16 + lk * 4;
            if (wsel == 0) {
#pragma unroll
                for (int jj = 0; jj < 4; ++jj)
                    qb[(size_t)(row0 + jj) * 128 + col] = f2bf(acc[mf][nf][jj]);
            } else if (wsel == 1) {
#pragma unroll
                for (int jj = 0; jj < 4; ++jj)
                    kb[(size_t)(row0 + jj) * 128 + col] = f2bf(acc[mf][nf][jj]);
            } else {
                const int bb2 = row0 >> 11, t0 = row0 & 2047;
                u16x4 v;
#pragma unroll
                for (int jj = 0; jj < 4; ++jj) v[jj] = f2bf(acc[mf][nf][jj]);
                *(u16x4*)(&vT[((size_t)bb2 * 128 + col) * 2048 + t0]) = v;
            }
        }
    }
}

// ---------------------------------------------------------------------------
// Kernel 2 (v10, unchanged): causal flash, KVBLK=128.
// ---------------------------------------------------------------------------
__global__ __launch_bounds__(256) void k_flash9(
    const u16* __restrict__ qb, const u16* __restrict__ kb, const u16* __restrict__ vT,
    u16* __restrict__ po, float* __restrict__ pm, float* __restrict__ pl)
{
    __shared__ u16 k_lds[128 * 128];     // 32 KB  [kv][d]
    __shared__ u16 v_lds[128 * 128];     // 32 KB  [d][kv]
    __shared__ u16 p_lds[4 * 16 * 128];  // 16 KB  per-wave 16x128
    const int tid  = threadIdx.x;
    const int lane = tid & 63, wid = tid >> 6;
    const int lrow = lane & 15, lk = lane >> 4;
    const int bx = blockIdx.x;
    const int b  = bx & 7;
    const int p  = (bx >> 3) & 15;
    const int z  = bx >> 7;

    const int za = z_small128(p);
    int qt, n, k, Z;
    if (z < za) { qt = p;      n = (p + 2) >> 1;  k = z;      Z = za;     }
    else        { qt = 31 - p; n = (33 - p) >> 1; k = z - za; Z = 8 - za; }
    const int t0 = (k * n) / Z;
    const int t1 = ((k + 1) * n) / Z;

    const int qrow0 = qt * 64;
    short8 qf[4];
    {
        const u16* qp = qb + ((size_t)b * 2048 + qrow0 + wid * 16 + lrow) * 128;
#pragma unroll
        for (int ks = 0; ks < 4; ++ks) qf[ks] = *(const short8*)(qp + ks * 32 + lk * 8);
    }
    f32x4 of[8];
#pragma unroll
    for (int i = 0; i < 8; ++i) of[i] = (f32x4){0.f, 0.f, 0.f, 0.f};
    float mrun[4], lsum[4];
#pragma unroll
    for (int j = 0; j < 4; ++j) { mrun[j] = -1e30f; lsum[j] = 0.f; }

    const u16* kbase = kb + (size_t)b * 2048 * 128;
    const u16* vbase = vT + (size_t)b * 128 * 2048;
    u16* pw = p_lds + wid * (16 * 128);

    for (int t = t0; t < t1; ++t) {
        const int kv0 = t << 7;
        __syncthreads();
#pragma unroll
        for (int i = 0; i < 8; ++i) {
            int ch = tid + i * 256;
            int row = ch >> 4, blk = ch & 15;
            gload_lds16(kbase + (size_t)(kv0 + row) * 128 + ((blk ^ (row & 7)) << 3),
                        &k_lds[ch * 8]);
        }
#pragma unroll
        for (int i = 0; i < 8; ++i) {
            int ch = tid + i * 256;
            int row = ch >> 4, blk = ch & 15;
            gload_lds16(vbase + (size_t)row * 2048 + kv0 + ((blk ^ (row & 7)) << 3),
                        &v_lds[ch * 8]);
        }
        __syncthreads();

        f32x4 sf[8];
#pragma unroll
        for (int nf = 0; nf < 8; ++nf) sf[nf] = (f32x4){0.f, 0.f, 0.f, 0.f};
#pragma unroll
        for (int ks = 0; ks < 4; ++ks)
#pragma unroll
            for (int nf = 0; nf < 8; ++nf) {
                int row = nf * 16 + lrow;
                int blk = (ks * 4 + lk) ^ (row & 7);
                short8 bfr = *(const short8*)(&k_lds[row * 128 + (blk << 3)]);
                sf[nf] = MFMA16x16x32(qf[ks], bfr, sf[nf], 0, 0, 0);
            }

        const bool needmask = (kv0 + 127 > qrow0 + wid * 16);
#pragma unroll
        for (int nf = 0; nf < 8; ++nf)
#pragma unroll
            for (int jj = 0; jj < 4; ++jj) {
                float s = sf[nf][jj] * 0.03125f;   // C^-0.5 = 1/32
                if (needmask &&
                    (kv0 + nf * 16 + lrow > qrow0 + wid * 16 + lk * 4 + jj)) s = -1e30f;
                sf[nf][jj] = s;
            }
        float mt[4];
#pragma unroll
        for (int jj = 0; jj < 4; ++jj) {
            float m01 = fmaxf(sf[0][jj], sf[1][jj]);
            float m23 = fmaxf(sf[2][jj], sf[3][jj]);
            float m45 = fmaxf(sf[4][jj], sf[5][jj]);
            float m67 = fmaxf(sf[6][jj], sf[7][jj]);
            mt[jj] = fmaxf(fmaxf(m01, m23), fmaxf(m45, m67));
        }
#pragma unroll
        for (int off = 1; off < 16; off <<= 1)
#pragma unroll
            for (int jj = 0; jj < 4; ++jj)
                mt[jj] = fmaxf(mt[jj], __shfl_xor(mt[jj], off));
        bool small = true;
#pragma unroll
        for (int jj = 0; jj < 4; ++jj) small = small && (mt[jj] <= mrun[jj] + 8.f);
        if (!__all(small)) {
#pragma unroll
            for (int jj = 0; jj < 4; ++jj) {
                float mnew = fmaxf(mrun[jj], mt[jj]);
                float sc   = __expf(mrun[jj] - mnew);
                mrun[jj]   = mnew;
                lsum[jj]  *= sc;
#pragma unroll
                for (int df = 0; df < 8; ++df) of[df][jj] *= sc;
            }
        }
        float rs[4] = {0.f, 0.f, 0.f, 0.f};
#pragma unroll
        for (int nf = 0; nf < 8; ++nf)
#pragma unroll
            for (int jj = 0; jj < 4; ++jj) {
                float e = __expf(sf[nf][jj] - mrun[jj]);
                sf[nf][jj] = e;
                rs[jj] += e;
            }
#pragma unroll
        for (int off = 1; off < 16; off <<= 1)
#pragma unroll
            for (int jj = 0; jj < 4; ++jj)
                rs[jj] += __shfl_xor(rs[jj], off);
#pragma unroll
        for (int jj = 0; jj < 4; ++jj) lsum[jj] += rs[jj];

#pragma unroll
        for (int nf = 0; nf < 8; ++nf)
#pragma unroll
            for (int jj = 0; jj < 4; ++jj) {
                int row = lk * 4 + jj;
                int col = nf * 16 + lrow;
                pw[row * 128 + (((col >> 3) ^ (row & 7)) << 3) + (col & 7)] = f2bf(sf[nf][jj]);
            }
        asm volatile("s_waitcnt lgkmcnt(0)" ::: "memory");
        __builtin_amdgcn_sched_barrier(0);
        short8 paf[4];
#pragma unroll
        for (int ks2 = 0; ks2 < 4; ++ks2) {
            int blk = (ks2 * 4 + lk) ^ (lrow & 7);
            paf[ks2] = *(const short8*)(&pw[lrow * 128 + (blk << 3)]);
        }
#pragma unroll
        for (int ks2 = 0; ks2 < 4; ++ks2)
#pragma unroll
            for (int df = 0; df < 8; ++df) {
                int row = df * 16 + lrow;
                int blk = (ks2 * 4 + lk) ^ (row & 7);
                short8 vf = *(const short8*)(&v_lds[row * 128 + (blk << 3)]);
                of[df] = MFMA16x16x32(paf[ks2], vf, of[df], 0, 0, 0);
            }
    }

    u16* poslab = po + (size_t)bx * (64 * 128);
#pragma unroll
    for (int df = 0; df < 8; ++df)
#pragma unroll
        for (int jj = 0; jj < 4; ++jj)
            poslab[(size_t)(wid * 16 + lk * 4 + jj) * 128 + df * 16 + lrow] = f2bf(of[df][jj]);
    if (lrow == 0) {
#pragma unroll
        for (int jj = 0; jj < 4; ++jj) {
            pm[(size_t)bx * 64 + wid * 16 + lk * 4 + jj] = mrun[jj];
            pl[(size_t)bx * 64 + wid * 16 + lk * 4 + jj] = lsum[jj];
        }
    }
}

// ---------------------------------------------------------------------------
// Kernel 3 (v5, unchanged): combine z-partials (17-tile pairing); po bf16.
// ---------------------------------------------------------------------------
__global__ __launch_bounds__(256) void k_combine(
    const u16* __restrict__ po, const float* __restrict__ pm, const float* __restrict__ pl,
    float* __restrict__ out)
{
    const int row  = blockIdx.x * 4 + (threadIdx.x >> 6);
    const int lane = threadIdx.x & 63;
    const int b  = row >> 11;
    const int t  = row & 2047;
    const int qt = t >> 6;
    const int r  = t & 63;

    const int p  = (qt < 16) ? qt : 31 - qt;
    const int za = z_small128(p);
    const int zlo = (qt < 16) ? 0 : za;
    const int zhi = (qt < 16) ? za : 8;

    float M = -1e30f;
    for (int z = zlo; z < zhi; ++z)
        M = fmaxf(M, pm[(size_t)(b + 8 * p + 128 * z) * 64 + r]);
    float den = 0.f, a0 = 0.f, a1 = 0.f;
    for (int z = zlo; z < zhi; ++z) {
        const int bxp = b + 8 * p + 128 * z;
        const float w = __expf(pm[(size_t)bxp * 64 + r] - M);
        den += w * pl[(size_t)bxp * 64 + r];
        const u16* slab = po + ((size_t)bxp * 64 + r) * 128;
        a0 += w * bf2f(slab[lane]);
        a1 += w * bf2f(slab[lane + 64]);
    }
    const float inv = 1.f / den;
    out[(size_t)row * 128 + lane]      = a0 * inv;
    out[(size_t)row * 128 + lane + 64] = a1 * inv;
}

// ---------------------------------------------------------------------------
extern "C" void kernel_launch(void* const* d_in, const int* in_sizes, int n_in,
                              void* d_out, int out_size, void* d_ws, size_t ws_size,
                              hipStream_t stream) {
    const float* x  = (const float*)d_in[0];
    const float* Wq = (const float*)d_in[1];
    const float* Wk = (const float*)d_in[2];
    const float* Wv = (const float*)d_in[3];
    float* out = (float*)d_out;

    char* ws = (char*)d_ws;
    u16*   qb  = (u16*)(ws);                         //  4 MB  [16384][128] bf16
    u16*   kb  = (u16*)(ws + (size_t)4  * 1048576);  //  4 MB  [16384][128] bf16
    u16*   vT  = (u16*)(ws + (size_t)8  * 1048576);  //  4 MB  [8][128][2048] bf16
    u16*   WTf = (u16*)(ws + (size_t)12 * 1048576);  //  0.75 MB fragment-ordered
    u16*   po  = (u16*)(ws + (size_t)13 * 1048576);  // 16.8 MB [1024][64][128] bf16
    float* pm  = (float*)(ws + (size_t)47 * 1048576);//  0.25 MB [1024][64]
    float* pl  = (float*)(ws + (size_t)48 * 1048576);//  0.25 MB [1024][64]

    k_transpose_wf<<<192, 256, 0, stream>>>(Wq, Wk, Wv, WTf);
    k_qkv_gemm12<<<256, 512, 0, stream>>>(x, WTf, qb, kb, vT);
    k_flash9<<<1024, 256, 0, stream>>>(qb, kb, vT, po, pm, pl);
    k_combine<<<4096, 256, 0, stream>>>(po, pm, pl, out);
}

// Round 21
// 74.575 us; speedup vs baseline: 1.0791x; 1.0791x over previous
//
#include <hip/hip_runtime.h>
#include <hip/hip_bf16.h>
#include <stdint.h>

typedef float f32x4 __attribute__((ext_vector_type(4)));
typedef float f32x4v __attribute__((ext_vector_type(4)));
typedef short short8 __attribute__((ext_vector_type(8)));
typedef unsigned short u16;
typedef unsigned short u16x8 __attribute__((ext_vector_type(8)));
typedef unsigned short u16x4 __attribute__((ext_vector_type(4)));

#define MFMA16x16x32 __builtin_amdgcn_mfma_f32_16x16x32_bf16

__device__ __forceinline__ u16 f2bf(float f) {
    unsigned int u = __builtin_bit_cast(unsigned int, f);
    u += 0x7fffu + ((u >> 16) & 1u);
    return (u16)(u >> 16);
}
__device__ __forceinline__ float bf2f(u16 v) {
    unsigned int u = ((unsigned int)v) << 16;
    return __builtin_bit_cast(float, u);
}

__device__ __forceinline__ void gload_lds16(const void* g, void* l) {
    __builtin_amdgcn_global_load_lds(
        (const __attribute__((address_space(1))) uint32_t*)g,
        (__attribute__((address_space(3))) uint32_t*)l, 16, 0, 0);
}

// z-blocks for the small qt of pair p (na = (p+2)>>1 kv128-tiles of the 17)
__device__ __forceinline__ int z_small128(int p) {
    int na = (p + 2) >> 1;
    int za = (8 * na + 16) / 17;
    za = za < 1 ? 1 : za;
    return za > 7 ? 7 : za;
}

// ---------------------------------------------------------------------------
// Kernel 0: W [1024,128] f32 -> WTf, MFMA-FRAGMENT-ORDERED bf16.
// Fragment f = (kt*2+ks)*24 + nc; chunk (f,lane) = 16B at WTf + f*1024 + lane*16.
// ---------------------------------------------------------------------------
__global__ void k_transpose_wf(const float* __restrict__ Wq, const float* __restrict__ Wk,
                               const float* __restrict__ Wv, u16* __restrict__ WTf) {
    int tid  = blockIdx.x * 256 + threadIdx.x;   // 0..49151
    int f    = tid >> 6;                         // 0..767
    int lane = tid & 63;
    int kt  = f / 48;
    int rem = f % 48;
    int ks  = rem / 24;
    int nc  = rem % 24;
    int col = nc * 16 + (lane & 15);
    int w   = col >> 7, n = col & 127;
    int k0  = kt * 64 + ks * 32 + (lane >> 4) * 8;
    const float* W = (w == 0) ? Wq : ((w == 1) ? Wk : Wv);
    u16x8 v;
#pragma unroll
    for (int j = 0; j < 8; ++j)
        v[j] = f2bf(W[(size_t)(k0 + j) * 128 + n]);
    *(u16x8*)(&WTf[(size_t)tid * 8]) = v;
}

// ---------------------------------------------------------------------------
// Kernel 1: FUSED QKV GEMM — gemm8 (best-measured, reverted verbatim).
// ---------------------------------------------------------------------------
__global__ __launch_bounds__(512) void k_qkv_gemm8(
    const float* __restrict__ x, const u16* __restrict__ WTf,
    u16* __restrict__ qb, u16* __restrict__ kb, u16* __restrict__ vT)
{
    __shared__ u16 abuf[2][64 * 64];     // 2 x 8 KB
    __shared__ u16 bbuf[2][384 * 64];    // 2 x 48 KB
    const int tid  = threadIdx.x;
    const int lane = tid & 63, wid = tid >> 6;
    const int wr = wid >> 2, wc = wid & 3;
    const int lrow = lane & 15, lk = lane >> 4;
    const int m0 = blockIdx.x * 64;

    const int arow = tid >> 3;            // 0..63
    const int aseg = tid & 7;             // 0..7 (8 f32 each)
    const float* xsrc = x + (size_t)(m0 + arow) * 1024 + aseg * 8;

    f32x4 acc[2][6];
#pragma unroll
    for (int i = 0; i < 2; ++i)
#pragma unroll
        for (int j = 0; j < 6; ++j) acc[i][j] = (f32x4){0.f, 0.f, 0.f, 0.f};

#define LOADA(s0, s1, ktv)                                                     \
    s0 = *(const f32x4v*)(xsrc + (ktv) * 64);                                  \
    s1 = *(const f32x4v*)(xsrc + (ktv) * 64 + 4);

#define STOREA(buf, s0, s1)                                                    \
    {   u16x8 v;                                                               \
        v[0]=f2bf(s0[0]); v[1]=f2bf(s0[1]); v[2]=f2bf(s0[2]); v[3]=f2bf(s0[3]); \
        v[4]=f2bf(s1[0]); v[5]=f2bf(s1[1]); v[6]=f2bf(s1[2]); v[7]=f2bf(s1[3]); \
        *(u16x8*)(&buf[arow * 64 + ((aseg ^ (arow & 7)) << 3)]) = v; }

#define ISSUEB(buf, ktv)                                                       \
    {   const u16* bsrc = WTf + (size_t)(ktv) * 24576;                         \
        _Pragma("unroll") for (int i = 0; i < 6; ++i) {                        \
            int c = tid + i * 512;                                             \
            gload_lds16(bsrc + c * 8, &buf[c * 8]);                            \
        } }

#define COMPUTE(ab, bb)                                                        \
    _Pragma("unroll") for (int ks = 0; ks < 2; ++ks) {                         \
        short8 af[2];                                                          \
        _Pragma("unroll") for (int mf = 0; mf < 2; ++mf) {                     \
            int row = wr * 32 + mf * 16 + lrow;                                \
            int blk = (ks * 4 + lk) ^ (row & 7);                               \
            af[mf] = *(const short8*)(&ab[row * 64 + (blk << 3)]);             \
        }                                                                      \
        _Pragma("unroll") for (int nf = 0; nf < 6; ++nf) {                     \
            short8 bfr = *(const short8*)(&bb[(ks * 24 + wc * 6 + nf) * 512 + lane * 8]); \
            _Pragma("unroll") for (int mf = 0; mf < 2; ++mf)                   \
                acc[mf][nf] = MFMA16x16x32(af[mf], bfr, acc[mf][nf], 0, 0, 0); \
        } }

#define WAITBAR()                                                              \
    asm volatile("s_waitcnt vmcnt(2) lgkmcnt(0)\n\ts_barrier" ::: "memory");   \
    __builtin_amdgcn_sched_barrier(0);

    f32x4v a0A, a1A, a0B, a1B;
    LOADA(a0A, a1A, 0);
    LOADA(a0B, a1B, 1);
    STOREA(abuf[0], a0A, a1A);
    ISSUEB(bbuf[0], 0);
    LOADA(a0A, a1A, 2);
    WAITBAR();

    for (int kt = 0; kt < 16; kt += 2) {
        {
            const int ktn = (kt + 1 < 16) ? kt + 1 : 15;
            ISSUEB(bbuf[1], ktn);
            __builtin_amdgcn_sched_barrier(0);
            COMPUTE(abuf[0], bbuf[0]);
            STOREA(abuf[1], a0B, a1B);
            const int kp = (kt + 3 < 16) ? kt + 3 : 15;
            LOADA(a0B, a1B, kp);
            WAITBAR();
        }
        {
            const int ktn = (kt + 2 < 16) ? kt + 2 : 15;
            ISSUEB(bbuf[0], ktn);
            __builtin_amdgcn_sched_barrier(0);
            COMPUTE(abuf[1], bbuf[1]);
            STOREA(abuf[0], a0A, a1A);
            const int kp = (kt + 4 < 16) ? kt + 4 : 15;
            LOADA(a0A, a1A, kp);
            WAITBAR();
        }
    }
#undef LOADA
#undef STOREA
#undef ISSUEB
#undef COMPUTE
#undef WAITBAR

#pragma unroll
    for (int nf = 0; nf < 6; ++nf) {
        const int gc   = wc * 96 + nf * 16 + lrow;
        const int wsel = gc >> 7;
        const int col  = gc & 127;
#pragma unroll
        for (int mf = 0; mf < 2; ++mf) {
            const int row0 = m0 + wr * 32 + mf * 16 + lk * 4;
            if (wsel == 0) {
#pragma unroll
                for (int jj = 0; jj < 4; ++jj)
                    qb[(size_t)(row0 + jj) * 128 + col] = f2bf(acc[mf][nf][jj]);
            } else if (wsel == 1) {
#pragma unroll
                for (int jj = 0; jj < 4; ++jj)
                    kb[(size_t)(row0 + jj) * 128 + col] = f2bf(acc[mf][nf][jj]);
            } else {
                const int bb = row0 >> 11, t0 = row0 & 2047;
                u16x4 v;
#pragma unroll
                for (int jj = 0; jj < 4; ++jj) v[jj] = f2bf(acc[mf][nf][jj]);
                *(u16x4*)(&vT[((size_t)bb * 128 + col) * 2048 + t0]) = v;
            }
        }
    }
}

// ---------------------------------------------------------------------------
// Kernel 2 (v10b): causal flash KVBLK=128 (R19) + s_setprio around MFMA
// clusters (T5: blocks are mutually unsynced; phase-diverse waves on a CU).
// ---------------------------------------------------------------------------
__global__ __launch_bounds__(256) void k_flash9(
    const u16* __restrict__ qb, const u16* __restrict__ kb, const u16* __restrict__ vT,
    u16* __restrict__ po, float* __restrict__ pm, float* __restrict__ pl)
{
    __shared__ u16 k_lds[128 * 128];     // 32 KB  [kv][d]
    __shared__ u16 v_lds[128 * 128];     // 32 KB  [d][kv]
    __shared__ u16 p_lds[4 * 16 * 128];  // 16 KB  per-wave 16x128
    const int tid  = threadIdx.x;
    const int lane = tid & 63, wid = tid >> 6;
    const int lrow = lane & 15, lk = lane >> 4;
    const int bx = blockIdx.x;
    const int b  = bx & 7;
    const int p  = (bx >> 3) & 15;
    const int z  = bx >> 7;

    const int za = z_small128(p);
    int qt, n, k, Z;
    if (z < za) { qt = p;      n = (p + 2) >> 1;  k = z;      Z = za;     }
    else        { qt = 31 - p; n = (33 - p) >> 1; k = z - za; Z = 8 - za; }
    const int t0 = (k * n) / Z;
    const int t1 = ((k + 1) * n) / Z;

    const int qrow0 = qt * 64;
    short8 qf[4];
    {
        const u16* qp = qb + ((size_t)b * 2048 + qrow0 + wid * 16 + lrow) * 128;
#pragma unroll
        for (int ks = 0; ks < 4; ++ks) qf[ks] = *(const short8*)(qp + ks * 32 + lk * 8);
    }
    f32x4 of[8];
#pragma unroll
    for (int i = 0; i < 8; ++i) of[i] = (f32x4){0.f, 0.f, 0.f, 0.f};
    float mrun[4], lsum[4];
#pragma unroll
    for (int j = 0; j < 4; ++j) { mrun[j] = -1e30f; lsum[j] = 0.f; }

    const u16* kbase = kb + (size_t)b * 2048 * 128;
    const u16* vbase = vT + (size_t)b * 128 * 2048;
    u16* pw = p_lds + wid * (16 * 128);

    for (int t = t0; t < t1; ++t) {
        const int kv0 = t << 7;
        __syncthreads();
#pragma unroll
        for (int i = 0; i < 8; ++i) {
            int ch = tid + i * 256;
            int row = ch >> 4, blk = ch & 15;
            gload_lds16(kbase + (size_t)(kv0 + row) * 128 + ((blk ^ (row & 7)) << 3),
                        &k_lds[ch * 8]);
        }
#pragma unroll
        for (int i = 0; i < 8; ++i) {
            int ch = tid + i * 256;
            int row = ch >> 4, blk = ch & 15;
            gload_lds16(vbase + (size_t)row * 2048 + kv0 + ((blk ^ (row & 7)) << 3),
                        &v_lds[ch * 8]);
        }
        __syncthreads();

        f32x4 sf[8];
#pragma unroll
        for (int nf = 0; nf < 8; ++nf) sf[nf] = (f32x4){0.f, 0.f, 0.f, 0.f};
        __builtin_amdgcn_s_setprio(1);
#pragma unroll
        for (int ks = 0; ks < 4; ++ks)
#pragma unroll
            for (int nf = 0; nf < 8; ++nf) {
                int row = nf * 16 + lrow;
                int blk = (ks * 4 + lk) ^ (row & 7);
                short8 bfr = *(const short8*)(&k_lds[row * 128 + (blk << 3)]);
                sf[nf] = MFMA16x16x32(qf[ks], bfr, sf[nf], 0, 0, 0);
            }
        __builtin_amdgcn_s_setprio(0);

        const bool needmask = (kv0 + 127 > qrow0 + wid * 16);
#pragma unroll
        for (int nf = 0; nf < 8; ++nf)
#pragma unroll
            for (int jj = 0; jj < 4; ++jj) {
                float s = sf[nf][jj] * 0.03125f;   // C^-0.5 = 1/32
                if (needmask &&
                    (kv0 + nf * 16 + lrow > qrow0 + wid * 16 + lk * 4 + jj)) s = -1e30f;
                sf[nf][jj] = s;
            }
        float mt[4];
#pragma unroll
        for (int jj = 0; jj < 4; ++jj) {
            float m01 = fmaxf(sf[0][jj], sf[1][jj]);
            float m23 = fmaxf(sf[2][jj], sf[3][jj]);
            float m45 = fmaxf(sf[4][jj], sf[5][jj]);
            float m67 = fmaxf(sf[6][jj], sf[7][jj]);
            mt[jj] = fmaxf(fmaxf(m01, m23), fmaxf(m45, m67));
        }
#pragma unroll
        for (int off = 1; off < 16; off <<= 1)
#pragma unroll
            for (int jj = 0; jj < 4; ++jj)
                mt[jj] = fmaxf(mt[jj], __shfl_xor(mt[jj], off));
        bool small = true;
#pragma unroll
        for (int jj = 0; jj < 4; ++jj) small = small && (mt[jj] <= mrun[jj] + 8.f);
        if (!__all(small)) {
#pragma unroll
            for (int jj = 0; jj < 4; ++jj) {
                float mnew = fmaxf(mrun[jj], mt[jj]);
                float sc   = __expf(mrun[jj] - mnew);
                mrun[jj]   = mnew;
                lsum[jj]  *= sc;
#pragma unroll
                for (int df = 0; df < 8; ++df) of[df][jj] *= sc;
            }
        }
        float rs[4] = {0.f, 0.f, 0.f, 0.f};
#pragma unroll
        for (int nf = 0; nf < 8; ++nf)
#pragma unroll
            for (int jj = 0; jj < 4; ++jj) {
                float e = __expf(sf[nf][jj] - mrun[jj]);
                sf[nf][jj] = e;
                rs[jj] += e;
            }
#pragma unroll
        for (int off = 1; off < 16; off <<= 1)
#pragma unroll
            for (int jj = 0; jj < 4; ++jj)
                rs[jj] += __shfl_xor(rs[jj], off);
#pragma unroll
        for (int jj = 0; jj < 4; ++jj) lsum[jj] += rs[jj];

#pragma unroll
        for (int nf = 0; nf < 8; ++nf)
#pragma unroll
            for (int jj = 0; jj < 4; ++jj) {
                int row = lk * 4 + jj;
                int col = nf * 16 + lrow;
                pw[row * 128 + (((col >> 3) ^ (row & 7)) << 3) + (col & 7)] = f2bf(sf[nf][jj]);
            }
        asm volatile("s_waitcnt lgkmcnt(0)" ::: "memory");
        __builtin_amdgcn_sched_barrier(0);
        short8 paf[4];
#pragma unroll
        for (int ks2 = 0; ks2 < 4; ++ks2) {
            int blk = (ks2 * 4 + lk) ^ (lrow & 7);
            paf[ks2] = *(const short8*)(&pw[lrow * 128 + (blk << 3)]);
        }
        __builtin_amdgcn_s_setprio(1);
#pragma unroll
        for (int ks2 = 0; ks2 < 4; ++ks2)
#pragma unroll
            for (int df = 0; df < 8; ++df) {
                int row = df * 16 + lrow;
                int blk = (ks2 * 4 + lk) ^ (row & 7);
                short8 vf = *(const short8*)(&v_lds[row * 128 + (blk << 3)]);
                of[df] = MFMA16x16x32(paf[ks2], vf, of[df], 0, 0, 0);
            }
        __builtin_amdgcn_s_setprio(0);
    }

    u16* poslab = po + (size_t)bx * (64 * 128);
#pragma unroll
    for (int df = 0; df < 8; ++df)
#pragma unroll
        for (int jj = 0; jj < 4; ++jj)
            poslab[(size_t)(wid * 16 + lk * 4 + jj) * 128 + df * 16 + lrow] = f2bf(of[df][jj]);
    if (lrow == 0) {
#pragma unroll
        for (int jj = 0; jj < 4; ++jj) {
            pm[(size_t)bx * 64 + wid * 16 + lk * 4 + jj] = mrun[jj];
            pl[(size_t)bx * 64 + wid * 16 + lk * 4 + jj] = lsum[jj];
        }
    }
}

// ---------------------------------------------------------------------------
// Kernel 3 (v5, unchanged): combine z-partials (17-tile pairing); po bf16.
// ---------------------------------------------------------------------------
__global__ __launch_bounds__(256) void k_combine(
    const u16* __restrict__ po, const float* __restrict__ pm, const float* __restrict__ pl,
    float* __restrict__ out)
{
    const int row  = blockIdx.x * 4 + (threadIdx.x >> 6);
    const int lane = threadIdx.x & 63;
    const int b  = row >> 11;
    const int t  = row & 2047;
    const int qt = t >> 6;
    const int r  = t & 63;

    const int p  = (qt < 16) ? qt : 31 - qt;
    const int za = z_small128(p);
    const int zlo = (qt < 16) ? 0 : za;
    const int zhi = (qt < 16) ? za : 8;

    float M = -1e30f;
    for (int z = zlo; z < zhi; ++z)
        M = fmaxf(M, pm[(size_t)(b + 8 * p + 128 * z) * 64 + r]);
    float den = 0.f, a0 = 0.f, a1 = 0.f;
    for (int z = zlo; z < zhi; ++z) {
        const int bxp = b + 8 * p + 128 * z;
        const float w = __expf(pm[(size_t)bxp * 64 + r] - M);
        den += w * pl[(size_t)bxp * 64 + r];
        const u16* slab = po + ((size_t)bxp * 64 + r) * 128;
        a0 += w * bf2f(slab[lane]);
        a1 += w * bf2f(slab[lane + 64]);
    }
    const float inv = 1.f / den;
    out[(size_t)row * 128 + lane]      = a0 * inv;
    out[(size_t)row * 128 + lane + 64] = a1 * inv;
}

// ---------------------------------------------------------------------------
extern "C" void kernel_launch(void* const* d_in, const int* in_sizes, int n_in,
                              void* d_out, int out_size, void* d_ws, size_t ws_size,
                              hipStream_t stream) {
    const float* x  = (const float*)d_in[0];
    const float* Wq = (const float*)d_in[1];
    const float* Wk = (const float*)d_in[2];
    const float* Wv = (const float*)d_in[3];
    float* out = (float*)d_out;

    char* ws = (char*)d_ws;
    u16*   qb  = (u16*)(ws);                         //  4 MB  [16384][128] bf16
    u16*   kb  = (u16*)(ws + (size_t)4  * 1048576);  //  4 MB  [16384][128] bf16
    u16*   vT  = (u16*)(ws + (size_t)8  * 1048576);  //  4 MB  [8][128][2048] bf16
    u16*   WTf = (u16*)(ws + (size_t)12 * 1048576);  //  0.75 MB fragment-ordered
    u16*   po  = (u16*)(ws + (size_t)13 * 1048576);  // 16.8 MB [1024][64][128] bf16
    float* pm  = (float*)(ws + (size_t)47 * 1048576);//  0.25 MB [1024][64]
    float* pl  = (float*)(ws + (size_t)48 * 1048576);//  0.25 MB [1024][64]

    k_transpose_wf<<<192, 256, 0, stream>>>(Wq, Wk, Wv, WTf);
    k_qkv_gemm8<<<256, 512, 0, stream>>>(x, WTf, qb, kb, vT);
    k_flash9<<<1024, 256, 0, stream>>>(qb, kb, vT, po, pm, pl);
    k_combine<<<4096, 256, 0, stream>>>(po, pm, pl, out);
}